// Round 3
// baseline (55.549 us; speedup 1.0000x reference)
//
#include <hip/hip_runtime.h>

// CrossConvV2: B=2, n=1024, d=3, f=3, m=26 probes, k=5 convs, o=6 out_feats.
// out[b,l] = [coords(3) | leakyrelu( (wf flat 78 * 10/n) @ W[k] + b[k] ) (30)]
// wf[b,l,m,ff] = sum_nn 1/(|c_nn - c_l - p_m|^2 + 10) * feats[nn,ff]
// |c_nn - c_l - p|^2 + 10 = |d|^2 + 19 - 2 d.p   (|p| = 3 for all probes)
//
// R2: (1) probe-dot CSE: t = fmaf(pz,dz,fmaf(py,dy,fmaf(px,dx,base))) with
// x innermost; probes grouped in rings sharing x then y -> GVN shares the
// inner FMAs (t-gen 39 -> ~19 ops per 13 probes). Zero coords skipped via
// if constexpr. (2) REPLICATE=3: grid x3 writing identical outputs, so our
// kernel (~60-75us) beats the 39us harness poison-fills into rocprof top-5
// and we finally get VALUBusy/Occupancy counters. Diagnostic round.

#define NPTS      1024
#define COEFF     10.0f
#define NEG       0.3f
#define REPLICATE 3

constexpr float PROBE[26][3] = {
  {-2.12132034f,  1.95984445f, -0.81179415f},
  {-2.12132034f,  1.95984445f,  0.81179415f},
  {-2.12132034f,  0.81179415f,  1.95984445f},
  {-2.12132034f, -0.81179415f,  1.95984445f},
  {-2.12132034f, -1.95984445f,  0.81179415f},
  {-2.12132034f, -1.95984445f, -0.81179415f},
  {-2.12132034f, -0.81179415f, -1.95984445f},
  {-2.12132034f,  0.81179415f, -1.95984445f},
  { 0.0f,         3.0f,         0.0f       },
  { 0.0f,         2.12132034f,  2.12132034f},
  { 0.0f,         0.0f,         3.0f       },
  { 0.0f,        -2.12132034f,  2.12132034f},
  { 0.0f,        -3.0f,         0.0f       },
  { 0.0f,        -2.12132034f, -2.12132034f},
  { 0.0f,         0.0f,        -3.0f       },
  { 0.0f,         2.12132034f, -2.12132034f},
  { 2.12132034f,  1.95984445f,  0.81179415f},
  { 2.12132034f,  0.81179415f,  1.95984445f},
  { 2.12132034f, -0.81179415f,  1.95984445f},
  { 2.12132034f, -1.95984445f,  0.81179415f},
  { 2.12132034f, -1.95984445f, -0.81179415f},
  { 2.12132034f, -0.81179415f, -1.95984445f},
  { 2.12132034f,  0.81179415f, -1.95984445f},
  { 2.12132034f,  1.95984445f, -0.81179415f},
  {-3.0f,         0.0f,         0.0f       },
  { 3.0f,         0.0f,         0.0f       },
};

// half0: ring x=-2.121 (8) + y/z-axials (4) + x-axials (2) = 14 probes
// half1: ring x=+2.121 (8) + diagonal quads (4)            = 12 probes
constexpr int H0[14] = {0,1,2,3,4,5,6,7, 8,12,10,14, 24,25};
constexpr int H1[14] = {16,17,18,19,20,21,22,23, 9,11,13,15, 0,0}; // pad

// wave64 sum-reduce via DPP (result valid in lane 63). rocPRIM pattern.
#define DPP_STEP(x, ctrl, rm, bm, bc)                                        \
  x += __int_as_float(__builtin_amdgcn_update_dpp(                           \
      0, __float_as_int(x), ctrl, rm, bm, bc))

__device__ __forceinline__ float wave_sum_to_lane63(float x) {
  DPP_STEP(x, 0x111, 0xf, 0xf, true);   // row_shr:1
  DPP_STEP(x, 0x112, 0xf, 0xf, true);   // row_shr:2
  DPP_STEP(x, 0x114, 0xf, 0xe, false);  // row_shr:4
  DPP_STEP(x, 0x118, 0xf, 0xc, false);  // row_shr:8
  DPP_STEP(x, 0x142, 0xa, 0xf, false);  // row_bcast:15 -> rows 1,3
  DPP_STEP(x, 0x143, 0xc, 0xf, false);  // row_bcast:31 -> rows 2,3
  return x;                              // lane 63 = full sum
}

template <int HALF, int J>
struct ProbeStep {
  static __device__ __forceinline__ void run(float base, float dx, float dy,
                                             float dz, float f0, float f1,
                                             float f2, float* acc) {
    ProbeStep<HALF, J - 1>::run(base, dx, dy, dz, f0, f1, f2, acc);
    constexpr int   m   = HALF ? H1[J] : H0[J];
    constexpr float px2 = -2.0f * PROBE[m][0];
    constexpr float py2 = -2.0f * PROBE[m][1];
    constexpr float pz2 = -2.0f * PROBE[m][2];
    float t = base;                         // x innermost: ring-shared CSE
    if constexpr (px2 != 0.0f) t = fmaf(px2, dx, t);
    if constexpr (py2 != 0.0f) t = fmaf(py2, dy, t);
    if constexpr (pz2 != 0.0f) t = fmaf(pz2, dz, t);
    const float w = __builtin_amdgcn_rcpf(t);   // 1/(sq+COEFF)
    acc[J * 3 + 0] = fmaf(w, f0, acc[J * 3 + 0]);
    acc[J * 3 + 1] = fmaf(w, f1, acc[J * 3 + 1]);
    acc[J * 3 + 2] = fmaf(w, f2, acc[J * 3 + 2]);
  }
};
template <int HALF>
struct ProbeStep<HALF, -1> {
  static __device__ __forceinline__ void run(float, float, float, float,
                                             float, float, float, float*) {}
};

template <int HALF>
__device__ __forceinline__ void run_main(const float* __restrict__ batch,
                                         int lane, float cx, float cy, float cz,
                                         float* acc) {
  constexpr int NP = HALF ? 12 : 14;
  for (int it = 0; it < NPTS / 64; ++it) {
    const float* prow = batch + (it * 64 + lane) * 6;
    const float2 q0 = *reinterpret_cast<const float2*>(prow);
    const float2 q1 = *reinterpret_cast<const float2*>(prow + 2);
    const float2 q2 = *reinterpret_cast<const float2*>(prow + 4);
    const float dx = q0.x - cx, dy = q0.y - cy, dz = q1.x - cz;
    const float f0 = q1.y, f1 = q2.x, f2 = q2.y;
    const float base = fmaf(dx, dx, fmaf(dy, dy, fmaf(dz, dz, 19.0f)));
    ProbeStep<HALF, NP - 1>::run(base, dx, dy, dz, f0, f1, f2, acc);
  }
}

template <int HALF>
__device__ __forceinline__ void reduce_store(float* acc, int lane, int cLocal,
                                             float sx[2][80], float scale) {
  constexpr int NP = HALF ? 12 : 14;
  #pragma unroll
  for (int j = 0; j < NP * 3; ++j)
    acc[j] = wave_sum_to_lane63(acc[j]) * scale;
  if (lane == 63) {
    #pragma unroll
    for (int j = 0; j < NP; ++j) {
      const int m = HALF ? H1[j] : H0[j];
      sx[cLocal][m * 3 + 0] = acc[j * 3 + 0];
      sx[cLocal][m * 3 + 1] = acc[j * 3 + 1];
      sx[cLocal][m * 3 + 2] = acc[j * 3 + 2];
    }
  }
}

__global__ __launch_bounds__(256, 4) void crossconv_kernel(
    const float* __restrict__ points,  // (2,1024,6)
    const float* __restrict__ W,       // (5,78,6)
    const float* __restrict__ bias,    // (5,6) flat 30
    float* __restrict__ out)           // (2,1024,33)
{
    __shared__ __align__(16) float sx[2][80];

    const int tid    = threadIdx.x;
    const int lane   = tid & 63;
    const int w      = tid >> 6;          // wave in block: 0..3
    const int cLocal = w >> 1;            // center within block: 0,1
    const int half   = w & 1;             // probe half: 0,1
    const int bid    = blockIdx.x & 1023; // REPLICATE copies write same data
    const int G      = bid * 2 + cLocal;  // global center 0..2047

    const float* batch = points + (G >> 10) * (NPTS * 6);
    const float* crow  = points + G * 6;
    const float  cx = crow[0], cy = crow[1], cz = crow[2];

    float acc[42];
    #pragma unroll
    for (int j = 0; j < 42; ++j) acc[j] = 0.f;

    if (half == 0) run_main<0>(batch, lane, cx, cy, cz, acc);
    else           run_main<1>(batch, lane, cx, cy, cz, acc);

    const float scale = COEFF / (float)NPTS;
    if (half == 0) reduce_store<0>(acc, lane, cLocal, sx, scale);
    else           reduce_store<1>(acc, lane, cLocal, sx, scale);
    __syncthreads();

    // tail: waves with half==0 do the 78->30 matmul + coords for their center
    if (half == 0) {
      float* orow = out + G * 33;
      if (lane < 30) {
        const int k = lane / 6, o = lane % 6;
        const float* Wk = W + k * (78 * 6) + o;  // W[k, t, o], stride 6 over t
        float h0 = bias[lane], h1 = 0.f, h2 = 0.f, h3 = 0.f;
        const float4* sxv = reinterpret_cast<const float4*>(sx[cLocal]);
        #pragma unroll
        for (int t4 = 0; t4 < 19; ++t4) {
          const float4 v = sxv[t4];
          h0 = fmaf(v.x, Wk[(t4 * 4 + 0) * 6], h0);
          h1 = fmaf(v.y, Wk[(t4 * 4 + 1) * 6], h1);
          h2 = fmaf(v.z, Wk[(t4 * 4 + 2) * 6], h2);
          h3 = fmaf(v.w, Wk[(t4 * 4 + 3) * 6], h3);
        }
        const float2 vt = *reinterpret_cast<const float2*>(&sx[cLocal][76]);
        h0 = fmaf(vt.x, Wk[76 * 6], h0);
        h1 = fmaf(vt.y, Wk[77 * 6], h1);
        float h = (h0 + h2) + (h1 + h3);
        h = (h > 0.f) ? h : NEG * h;
        orow[3 + lane] = h;
      } else if (lane < 33) {
        orow[lane - 30] = (lane == 30) ? cx : ((lane == 31) ? cy : cz);
      }
    }
}

extern "C" void kernel_launch(void* const* d_in, const int* in_sizes, int n_in,
                              void* d_out, int out_size, void* d_ws, size_t ws_size,
                              hipStream_t stream) {
    const float* points = (const float*)d_in[0];  // 2*1024*6
    const float* W      = (const float*)d_in[1];  // 5*78*6
    const float* bias   = (const float*)d_in[2];  // 30
    float* out          = (float*)d_out;          // 2*1024*33
    // 1024 logical blocks x REPLICATE (identical outputs; makes our kernel
    // outlast the 39us harness fills so rocprof top-5 shows OUR counters)
    crossconv_kernel<<<1024 * REPLICATE, 256, 0, stream>>>(points, W, bias, out);
}

// Round 4
// 23.898 us; speedup vs baseline: 2.3244x; 2.3244x over previous
//
#include <hip/hip_runtime.h>

// CrossConvV2: B=2, n=1024, d=3, f=3, m=26 probes, k=5 convs, o=6 out_feats.
// out[b,l] = [coords(3) | leakyrelu( (wf flat 78 * 10/n) @ W[k] + b[k] ) (30)]
// wf[b,l,m,ff] = sum_nn 1/(|c_nn - c_l - p_m|^2 + 10) * feats[nn,ff]
// |c_nn - c_l - p|^2 + 10 = |d|^2 + 19 - 2 d.p   (|p| = 3 for all probes)
//
// R3: batched reciprocals. R2 counters showed v_rcp_f32 ~16 cyc/wave64
// (~45% of VALU issue). rcp(t0*t1*t2*t3) + 9 muls replaces 4 rcps:
// 64 -> 34 cyc per quad. t in [10,140], products <= 4e8: fp32-safe.

#define NPTS      1024
#define COEFF     10.0f
#define NEG       0.3f

constexpr float PROBE[26][3] = {
  {-2.12132034f,  1.95984445f, -0.81179415f},
  {-2.12132034f,  1.95984445f,  0.81179415f},
  {-2.12132034f,  0.81179415f,  1.95984445f},
  {-2.12132034f, -0.81179415f,  1.95984445f},
  {-2.12132034f, -1.95984445f,  0.81179415f},
  {-2.12132034f, -1.95984445f, -0.81179415f},
  {-2.12132034f, -0.81179415f, -1.95984445f},
  {-2.12132034f,  0.81179415f, -1.95984445f},
  { 0.0f,         3.0f,         0.0f       },
  { 0.0f,         2.12132034f,  2.12132034f},
  { 0.0f,         0.0f,         3.0f       },
  { 0.0f,        -2.12132034f,  2.12132034f},
  { 0.0f,        -3.0f,         0.0f       },
  { 0.0f,        -2.12132034f, -2.12132034f},
  { 0.0f,         0.0f,        -3.0f       },
  { 0.0f,         2.12132034f, -2.12132034f},
  { 2.12132034f,  1.95984445f,  0.81179415f},
  { 2.12132034f,  0.81179415f,  1.95984445f},
  { 2.12132034f, -0.81179415f,  1.95984445f},
  { 2.12132034f, -1.95984445f,  0.81179415f},
  { 2.12132034f, -1.95984445f, -0.81179415f},
  { 2.12132034f, -0.81179415f, -1.95984445f},
  { 2.12132034f,  0.81179415f, -1.95984445f},
  { 2.12132034f,  1.95984445f, -0.81179415f},
  {-3.0f,         0.0f,         0.0f       },
  { 3.0f,         0.0f,         0.0f       },
};

// half0: ring x=-2.121 (8) + y/z-axials (4) + x-axials (2) = 14 probes
// half1: ring x=+2.121 (8) + diagonal quads (4)            = 12 probes
constexpr int H0[14] = {0,1,2,3,4,5,6,7, 8,12,10,14, 24,25};
constexpr int H1[14] = {16,17,18,19,20,21,22,23, 9,11,13,15, 0,0}; // pad

// wave64 sum-reduce via DPP (result valid in lane 63). rocPRIM pattern.
#define DPP_STEP(x, ctrl, rm, bm, bc)                                        \
  x += __int_as_float(__builtin_amdgcn_update_dpp(                           \
      0, __float_as_int(x), ctrl, rm, bm, bc))

__device__ __forceinline__ float wave_sum_to_lane63(float x) {
  DPP_STEP(x, 0x111, 0xf, 0xf, true);   // row_shr:1
  DPP_STEP(x, 0x112, 0xf, 0xf, true);   // row_shr:2
  DPP_STEP(x, 0x114, 0xf, 0xe, false);  // row_shr:4
  DPP_STEP(x, 0x118, 0xf, 0xc, false);  // row_shr:8
  DPP_STEP(x, 0x142, 0xa, 0xf, false);  // row_bcast:15 -> rows 1,3
  DPP_STEP(x, 0x143, 0xc, 0xf, false);  // row_bcast:31 -> rows 2,3
  return x;                              // lane 63 = full sum
}

// t-generation with compile-time zero-skip; shared subtrees CSE via GVN
template <int HALF, int J>
struct TGen {
  static __device__ __forceinline__ void run(float base, float dx, float dy,
                                             float dz, float* t) {
    TGen<HALF, J - 1>::run(base, dx, dy, dz, t);
    constexpr int   m   = HALF ? H1[J] : H0[J];
    constexpr float px2 = -2.0f * PROBE[m][0];
    constexpr float py2 = -2.0f * PROBE[m][1];
    constexpr float pz2 = -2.0f * PROBE[m][2];
    float v = base;                         // x innermost: ring-shared CSE
    if constexpr (px2 != 0.0f) v = fmaf(px2, dx, v);
    if constexpr (py2 != 0.0f) v = fmaf(py2, dy, v);
    if constexpr (pz2 != 0.0f) v = fmaf(pz2, dz, v);
    t[J] = v;
  }
};
template <int HALF>
struct TGen<HALF, -1> {
  static __device__ __forceinline__ void run(float, float, float, float, float*) {}
};

// batched reciprocal: 1 rcp + 9 mul for 4 values (vs 4 rcp)
__device__ __forceinline__ void rcp4(const float* t, float* w) {
  const float p01 = t[0] * t[1], p23 = t[2] * t[3];
  const float r   = __builtin_amdgcn_rcpf(p01 * p23);
  const float r01 = p23 * r, r23 = p01 * r;
  w[0] = t[1] * r01;  w[1] = t[0] * r01;
  w[2] = t[3] * r23;  w[3] = t[2] * r23;
}
__device__ __forceinline__ void rcp2(const float* t, float* w) {
  const float r = __builtin_amdgcn_rcpf(t[0] * t[1]);
  w[0] = t[1] * r;  w[1] = t[0] * r;
}

template <int HALF>
__device__ __forceinline__ void run_main(const float* __restrict__ batch,
                                         int lane, float cx, float cy, float cz,
                                         float* acc) {
  constexpr int NP = HALF ? 12 : 14;
  for (int it = 0; it < NPTS / 64; ++it) {
    const float* prow = batch + (it * 64 + lane) * 6;
    const float2 q0 = *reinterpret_cast<const float2*>(prow);
    const float2 q1 = *reinterpret_cast<const float2*>(prow + 2);
    const float2 q2 = *reinterpret_cast<const float2*>(prow + 4);
    const float dx = q0.x - cx, dy = q0.y - cy, dz = q1.x - cz;
    const float f0 = q1.y, f1 = q2.x, f2 = q2.y;
    const float base = fmaf(dx, dx, fmaf(dy, dy, fmaf(dz, dz, 19.0f)));

    float t[NP], w[NP];
    TGen<HALF, NP - 1>::run(base, dx, dy, dz, t);
    rcp4(t + 0, w + 0);
    rcp4(t + 4, w + 4);
    rcp4(t + 8, w + 8);
    if constexpr (NP == 14) rcp2(t + 12, w + 12);

    #pragma unroll
    for (int j = 0; j < NP; ++j) {
      acc[j * 3 + 0] = fmaf(w[j], f0, acc[j * 3 + 0]);
      acc[j * 3 + 1] = fmaf(w[j], f1, acc[j * 3 + 1]);
      acc[j * 3 + 2] = fmaf(w[j], f2, acc[j * 3 + 2]);
    }
  }
}

template <int HALF>
__device__ __forceinline__ void reduce_store(float* acc, int lane, int cLocal,
                                             float sx[2][80], float scale) {
  constexpr int NP = HALF ? 12 : 14;
  #pragma unroll
  for (int j = 0; j < NP * 3; ++j)
    acc[j] = wave_sum_to_lane63(acc[j]) * scale;
  if (lane == 63) {
    #pragma unroll
    for (int j = 0; j < NP; ++j) {
      const int m = HALF ? H1[j] : H0[j];
      sx[cLocal][m * 3 + 0] = acc[j * 3 + 0];
      sx[cLocal][m * 3 + 1] = acc[j * 3 + 1];
      sx[cLocal][m * 3 + 2] = acc[j * 3 + 2];
    }
  }
}

__global__ __launch_bounds__(256, 4) void crossconv_kernel(
    const float* __restrict__ points,  // (2,1024,6)
    const float* __restrict__ W,       // (5,78,6)
    const float* __restrict__ bias,    // (5,6) flat 30
    float* __restrict__ out)           // (2,1024,33)
{
    __shared__ __align__(16) float sx[2][80];

    const int tid    = threadIdx.x;
    const int lane   = tid & 63;
    const int w      = tid >> 6;          // wave in block: 0..3
    const int cLocal = w >> 1;            // center within block: 0,1
    const int half   = w & 1;             // probe half: 0,1
    const int G      = blockIdx.x * 2 + cLocal;   // global center 0..2047

    const float* batch = points + (G >> 10) * (NPTS * 6);
    const float* crow  = points + G * 6;
    const float  cx = crow[0], cy = crow[1], cz = crow[2];

    float acc[42];
    #pragma unroll
    for (int j = 0; j < 42; ++j) acc[j] = 0.f;

    if (half == 0) run_main<0>(batch, lane, cx, cy, cz, acc);
    else           run_main<1>(batch, lane, cx, cy, cz, acc);

    const float scale = COEFF / (float)NPTS;
    if (half == 0) reduce_store<0>(acc, lane, cLocal, sx, scale);
    else           reduce_store<1>(acc, lane, cLocal, sx, scale);
    __syncthreads();

    // tail: waves with half==0 do the 78->30 matmul + coords for their center
    if (half == 0) {
      float* orow = out + G * 33;
      if (lane < 30) {
        const int k = lane / 6, o = lane % 6;
        const float* Wk = W + k * (78 * 6) + o;  // W[k, t, o], stride 6 over t
        float h0 = bias[lane], h1 = 0.f, h2 = 0.f, h3 = 0.f;
        const float4* sxv = reinterpret_cast<const float4*>(sx[cLocal]);
        #pragma unroll
        for (int t4 = 0; t4 < 19; ++t4) {
          const float4 v = sxv[t4];
          h0 = fmaf(v.x, Wk[(t4 * 4 + 0) * 6], h0);
          h1 = fmaf(v.y, Wk[(t4 * 4 + 1) * 6], h1);
          h2 = fmaf(v.z, Wk[(t4 * 4 + 2) * 6], h2);
          h3 = fmaf(v.w, Wk[(t4 * 4 + 3) * 6], h3);
        }
        const float2 vt = *reinterpret_cast<const float2*>(&sx[cLocal][76]);
        h0 = fmaf(vt.x, Wk[76 * 6], h0);
        h1 = fmaf(vt.y, Wk[77 * 6], h1);
        float h = (h0 + h2) + (h1 + h3);
        h = (h > 0.f) ? h : NEG * h;
        orow[3 + lane] = h;
      } else if (lane < 33) {
        orow[lane - 30] = (lane == 30) ? cx : ((lane == 31) ? cy : cz);
      }
    }
}

extern "C" void kernel_launch(void* const* d_in, const int* in_sizes, int n_in,
                              void* d_out, int out_size, void* d_ws, size_t ws_size,
                              hipStream_t stream) {
    const float* points = (const float*)d_in[0];  // 2*1024*6
    const float* W      = (const float*)d_in[1];  // 5*78*6
    const float* bias   = (const float*)d_in[2];  // 30
    float* out          = (float*)d_out;          // 2*1024*33
    // 1024 blocks x 4 waves = 2048 centers x 2 probe-halves
    crossconv_kernel<<<1024, 256, 0, stream>>>(points, W, bias, out);
}